// Round 9
// baseline (232.529 us; speedup 1.0000x reference)
//
#include <hip/hip_runtime.h>
#include <math.h>

#define BB 64
#define TT 256
#define KK 32
#define VV 32
#define CH 64                    // output rows owned per block
#define PH 32                    // steps per phase
#define ROWS (CH + PH)           // 96 rows covered per block
#define NPHASE ((TT + KK) / PH)  // 9 phases * 32 = 288 steps
#define BPB (TT / CH)            // 4 chunks per batch
#define NW (ROWS / 16)           // 6 waves per block
#define NTHR (NW * 64)           // 384 threads

// workspace layout (floats)
#define RW_OFF    0                       // K*K
#define WOP_OFF   1024                    // 37*K
#define ATOM_OFF  2240                    // B*T*K
#define STATE_OFF (ATOM_OFF + BB*TT*KK)   // B*T*K (phase-boundary handoff)
#define FLAG_OFF  (STATE_OFF + BB*TT*KK)  // BB*BPB ints

typedef __attribute__((ext_vector_type(8))) short short8;
typedef __attribute__((ext_vector_type(4))) float floatx4;
typedef __attribute__((ext_vector_type(4))) int intx4;

__device__ __forceinline__ float myrelu(float z) {
    return fmaf(0.01f, z, 0.99f * __builtin_amdgcn_fmed3f(z, 0.f, 1.f));
}
__device__ __forceinline__ ushort f2bf(float f) {
    union { float f; unsigned int u; } v; v.f = f;
    unsigned int r = v.u + 0x7fffu + ((v.u >> 16) & 1u);
    return (ushort)(r >> 16);
}
__device__ __forceinline__ float dpp_shl1_f(float v) {
    // lane n <- lane n+1 within each 16-lane row; lane 15 of row -> 0
    return __int_as_float(__builtin_amdgcn_update_dpp(
        0, __float_as_int(v), 0x101, 0xF, 0xF, true));
}

// --- softmaxes of w_op (32 x 37) and w_right (32 x 33) ---
__global__ void prep_kernel(const float* __restrict__ w_right,
                            const float* __restrict__ w_op,
                            float* __restrict__ ws) {
    int tid = threadIdx.x;
    float* rw  = ws + RW_OFF;   // rw[k*K + j] = softmax(w_right)[j][k]
    float* wop = ws + WOP_OFF;  // wop[i*K + k] = sm_op[k][i]
    if (tid < KK) {
        float v[37];
        float m = -1e30f;
        #pragma unroll
        for (int i = 0; i < 37; ++i) { v[i] = w_op[tid * 37 + i]; m = fmaxf(m, v[i]); }
        float s = 0.f;
        #pragma unroll
        for (int i = 0; i < 37; ++i) { v[i] = expf(v[i] - m); s += v[i]; }
        float inv = 1.f / s;
        #pragma unroll
        for (int i = 0; i < 37; ++i) wop[i * KK + tid] = v[i] * inv;
    } else if (tid < 2 * KK) {
        int r = tid - KK;
        float v[KK + 1];
        float m = -1e30f;
        #pragma unroll
        for (int i = 0; i <= KK; ++i) { v[i] = w_right[r * (KK + 1) + i]; m = fmaxf(m, v[i]); }
        float s = 0.f;
        #pragma unroll
        for (int i = 0; i <= KK; ++i) { v[i] = expf(v[i] - m); s += v[i]; }
        float inv = 1.f / s;
        #pragma unroll
        for (int c = 0; c < KK; ++c) rw[c * KK + r] = v[c] * inv;
    }
}

// --- atom_x = x @ atom_w ; zero the handshake flags ---
__global__ void atomx_kernel(const float* __restrict__ x, float* __restrict__ ws) {
    const float* aw = ws + WOP_OFF + 5 * KK;
    float* atom = ws + ATOM_OFF;
    int tid = threadIdx.x;
    if (blockIdx.x == 0 && tid < BB * BPB) ((int*)(ws + FLAG_OFF))[tid] = 0;
    int k  = tid & (KK - 1);
    int bt = blockIdx.x * 8 + (tid >> 5);
    const float* xrow = x + bt * VV;
    float acc = 0.f;
    #pragma unroll
    for (int v = 0; v < VV; ++v) acc = fmaf(xrow[v], aw[v * KK + k], acc);
    atom[bt * KK + k] = acc;
}

// --- all 288 steps; r4 geometry + folded 4-MFMA math + lean handshake ---
__global__ __launch_bounds__(NTHR, 1)
void phase_all_kernel(float* __restrict__ ws, float* __restrict__ out) {
    __shared__ float brow[2][NW + 1][36];   // 16-row tile-boundary rows, dbuf (~2KB)

    const float* rw   = ws + RW_OFF;
    const float* wop  = ws + WOP_OFF;
    const float* atom = ws + ATOM_OFF;
    float*      state = ws + STATE_OFF;
    int*        flags = (int*)(ws + FLAG_OFF);

    int tid  = threadIdx.x;
    int lane = tid & 63;
    int rt   = tid >> 6;        // wave = row-tile 0..5
    int lr   = lane & 15;
    int hi   = lane >> 4;
    int b  = blockIdx.x / BPB;
    int c  = blockIdx.x % BPB;
    int lo = c * CH;
    int t0 = lo + rt * 16 + lr;            // this lane's global row
    bool active = (lo + rt * 16) < TT;     // wave-uniform
    bool l15 = (lr == 15);
    bool h3  = (hi == 3);

    for (int i = tid; i < 2 * (NW + 1) * 36; i += NTHR)
        (&brow[0][0][0])[i] = 0.f;

    float* gs = state + (size_t)b * TT * KK;

    float y0 = 0.f, y1 = 0.f, y2 = 0.f, y3 = 0.f;
    float y4 = 0.f, y5 = 0.f, y6 = 0.f, y7 = 0.f;

    // per-lane constants for cols hi*8..hi*8+7
    floatx4 c0a, c0b;
    float w4c0, w4c1, w4c2, w4c3, w4c4, w4c5, w4c6, w4c7;
    {
        float4 a0 = make_float4(0, 0, 0, 0), a1 = make_float4(0, 0, 0, 0);
        if (t0 < TT) {
            a0 = *reinterpret_cast<const float4*>(&atom[((size_t)b * TT + t0) * KK + hi * 8]);
            a1 = *reinterpret_cast<const float4*>(&atom[((size_t)b * TT + t0) * KK + hi * 8 + 4]);
        }
        const float* w1p = wop + 1 * KK + hi * 8;
        const float* w2p = wop + 2 * KK + hi * 8;
        const float* w4p = wop + 4 * KK + hi * 8;
        c0a = (floatx4){a0.x + w1p[0] - w2p[0] - w4p[0],
                        a0.y + w1p[1] - w2p[1] - w4p[1],
                        a0.z + w1p[2] - w2p[2] - w4p[2],
                        a0.w + w1p[3] - w2p[3] - w4p[3]};
        c0b = (floatx4){a1.x + w1p[4] - w2p[4] - w4p[4],
                        a1.y + w1p[5] - w2p[5] - w4p[5],
                        a1.z + w1p[6] - w2p[6] - w4p[6],
                        a1.w + w1p[7] - w2p[7] - w4p[7]};
        w4c0 = 0.99f * w4p[0]; w4c1 = 0.99f * w4p[1];
        w4c2 = 0.99f * w4p[2]; w4c3 = 0.99f * w4p[3];
        w4c4 = 0.99f * w4p[4]; w4c5 = 0.99f * w4p[5];
        w4c6 = 0.99f * w4p[6]; w4c7 = 0.99f * w4p[7];
    }

    // A' and N fragments (folds verified r6-r8):
    // A'[k][col] = rw[k][col]*(w2+w4) + (k==col+1)*d1p
    // N [k][col] = (k==col)*0.01*w4 + (k==col+1)*w3
    short8 af0, af1, nf0, nf1;
    {
        int col0 = ((lr >> 2) << 3) | (lr & 3);
        int col1 = col0 + 4;
        float w1a = wop[1 * KK + col0], w2a = wop[2 * KK + col0];
        float w3a = wop[3 * KK + col0], w4a = wop[4 * KK + col0];
        float w1b = wop[1 * KK + col1], w2b = wop[2 * KK + col1];
        float w3b = wop[3 * KK + col1], w4b = wop[4 * KK + col1];
        float sa = w2a + w4a, sb = w2b + w4b;
        float da = (w2a - w1a) + 0.01f * w4a;
        float db = (w2b - w1b) + 0.01f * w4b;
        int k0 = hi * 8;
        #pragma unroll
        for (int q = 0; q < 8; ++q) {
            int k = k0 + q;
            af0[q] = (short)f2bf(rw[k * KK + col0] * sa + ((k == col0 + 1) ? da : 0.f));
            af1[q] = (short)f2bf(rw[k * KK + col1] * sb + ((k == col1 + 1) ? db : 0.f));
            nf0[q] = (short)f2bf((k == col0) ? 0.01f * w4a : ((k == col0 + 1) ? w3a : 0.f));
            nf1[q] = (short)f2bf((k == col1) ? 0.01f * w4b : ((k == col1 + 1) ? w3b : 0.f));
        }
    }

    int pidx = ((lane + 16) & 63) << 2;   // bpermute addr for lane+16
    __syncthreads();

    for (int p = 0; p < NPHASE; ++p) {
        for (int s = 0; s < PH; ++s) {
            int cur = s & 1;
            if (active) {
                // neighbor row via DPP; 16-row tile boundary via broadcast LDS read
                float nx0 = dpp_shl1_f(y0), nx1 = dpp_shl1_f(y1);
                float nx2 = dpp_shl1_f(y2), nx3 = dpp_shl1_f(y3);
                float nx4 = dpp_shl1_f(y4), nx5 = dpp_shl1_f(y5);
                float nx6 = dpp_shl1_f(y6), nx7 = dpp_shl1_f(y7);
                float4 n0 = *reinterpret_cast<const float4*>(&brow[cur][rt + 1][hi * 8]);
                float4 n1 = *reinterpret_cast<const float4*>(&brow[cur][rt + 1][hi * 8 + 4]);
                nx0 = l15 ? n0.x : nx0;  nx1 = l15 ? n0.y : nx1;
                nx2 = l15 ? n0.z : nx2;  nx3 = l15 ? n0.w : nx3;
                nx4 = l15 ? n1.x : nx4;  nx5 = l15 ? n1.y : nx5;
                nx6 = l15 ? n1.z : nx6;  nx7 = l15 ? n1.w : nx7;
                float lbr = __int_as_float(__builtin_amdgcn_ds_bpermute(pidx, __float_as_int(y0)));
                float lb  = h3 ? 0.f : lbr;

                // bf16 fragments: own row + neighbor row (post-fix, so boundary free)
                unsigned bw0, bw1, bw2, bw3, nw0, nw1, nw2, nw3;
                asm("v_cvt_pk_bf16_f32 %0, %1, %2" : "=v"(bw0) : "v"(y0), "v"(y1));
                asm("v_cvt_pk_bf16_f32 %0, %1, %2" : "=v"(bw1) : "v"(y2), "v"(y3));
                asm("v_cvt_pk_bf16_f32 %0, %1, %2" : "=v"(bw2) : "v"(y4), "v"(y5));
                asm("v_cvt_pk_bf16_f32 %0, %1, %2" : "=v"(bw3) : "v"(y6), "v"(y7));
                asm("v_cvt_pk_bf16_f32 %0, %1, %2" : "=v"(nw0) : "v"(nx0), "v"(nx1));
                asm("v_cvt_pk_bf16_f32 %0, %1, %2" : "=v"(nw1) : "v"(nx2), "v"(nx3));
                asm("v_cvt_pk_bf16_f32 %0, %1, %2" : "=v"(nw2) : "v"(nx4), "v"(nx5));
                asm("v_cvt_pk_bf16_f32 %0, %1, %2" : "=v"(nw3) : "v"(nx6), "v"(nx7));
                short8 bv = __builtin_bit_cast(short8,
                    (intx4){(int)bw0, (int)bw1, (int)bw2, (int)bw3});
                short8 nv = __builtin_bit_cast(short8,
                    (intx4){(int)nw0, (int)nw1, (int)nw2, (int)nw3});

                floatx4 acc0 = __builtin_amdgcn_mfma_f32_16x16x32_bf16(af0, bv, c0a, 0, 0, 0);
                floatx4 acc1 = __builtin_amdgcn_mfma_f32_16x16x32_bf16(af1, bv, c0b, 0, 0, 0);
                acc0 = __builtin_amdgcn_mfma_f32_16x16x32_bf16(nf0, nv, acc0, 0, 0, 0);
                acc1 = __builtin_amdgcn_mfma_f32_16x16x32_bf16(nf1, nv, acc1, 0, 0, 0);

                // tail, ascending (le = old y[q+1] not yet overwritten)
                {
                    float sm = y1 + nx0, t = __builtin_amdgcn_fmed3f(sm, 1.f, 2.f);
                    y0 = myrelu(fmaf(t, w4c0, acc0[0]));
                }
                {
                    float sm = y2 + nx1, t = __builtin_amdgcn_fmed3f(sm, 1.f, 2.f);
                    y1 = myrelu(fmaf(t, w4c1, acc0[1]));
                }
                {
                    float sm = y3 + nx2, t = __builtin_amdgcn_fmed3f(sm, 1.f, 2.f);
                    y2 = myrelu(fmaf(t, w4c2, acc0[2]));
                }
                {
                    float sm = y4 + nx3, t = __builtin_amdgcn_fmed3f(sm, 1.f, 2.f);
                    y3 = myrelu(fmaf(t, w4c3, acc0[3]));
                }
                {
                    float sm = y5 + nx4, t = __builtin_amdgcn_fmed3f(sm, 1.f, 2.f);
                    y4 = myrelu(fmaf(t, w4c4, acc1[0]));
                }
                {
                    float sm = y6 + nx5, t = __builtin_amdgcn_fmed3f(sm, 1.f, 2.f);
                    y5 = myrelu(fmaf(t, w4c5, acc1[1]));
                }
                {
                    float sm = y7 + nx6, t = __builtin_amdgcn_fmed3f(sm, 1.f, 2.f);
                    y6 = myrelu(fmaf(t, w4c6, acc1[2]));
                }
                {
                    float sm = lb + nx7, t = __builtin_amdgcn_fmed3f(sm, 1.f, 2.f);
                    y7 = myrelu(fmaf(t, w4c7, acc1[3]));
                }

                if (lr == 0) {
                    float* wp = &brow[cur ^ 1][rt][hi * 8];
                    *reinterpret_cast<float4*>(wp)     = make_float4(y0, y1, y2, y3);
                    *reinterpret_cast<float4*>(wp + 4) = make_float4(y4, y5, y6, y7);
                }
            }
            __syncthreads();
        }
        if (p == NPHASE - 1) break;

        // ---- phase boundary: plain coalesced publish + release flag (no fence) ----
        if (rt < 2 && c > 0) {     // publish owned rows 0..31
            float* gp = gs + (size_t)t0 * KK + hi * 8;
            *reinterpret_cast<float4*>(gp)     = make_float4(y0, y1, y2, y3);
            *reinterpret_cast<float4*>(gp + 4) = make_float4(y4, y5, y6, y7);
        }
        __syncthreads();
        if (tid == 0) {
            if (c > 0)
                __hip_atomic_store(&flags[b * BPB + c], p + 1,
                                   __ATOMIC_RELEASE, __HIP_MEMORY_SCOPE_AGENT);
            if (c < BPB - 1) {
                while (__hip_atomic_load(&flags[b * BPB + c + 1],
                                         __ATOMIC_ACQUIRE, __HIP_MEMORY_SCOPE_AGENT) < p + 1)
                    __builtin_amdgcn_s_sleep(2);
            }
        }
        __syncthreads();
        if (active && rt >= CH / 16) {      // halo waves 4,5 reload fresh rows
            unsigned long long* gp =
                reinterpret_cast<unsigned long long*>(gs + (size_t)t0 * KK + hi * 8);
            unsigned long long u0 = __hip_atomic_load(&gp[0], __ATOMIC_RELAXED, __HIP_MEMORY_SCOPE_AGENT);
            unsigned long long u1 = __hip_atomic_load(&gp[1], __ATOMIC_RELAXED, __HIP_MEMORY_SCOPE_AGENT);
            unsigned long long u2 = __hip_atomic_load(&gp[2], __ATOMIC_RELAXED, __HIP_MEMORY_SCOPE_AGENT);
            unsigned long long u3 = __hip_atomic_load(&gp[3], __ATOMIC_RELAXED, __HIP_MEMORY_SCOPE_AGENT);
            y0 = __uint_as_float((unsigned)u0); y1 = __uint_as_float((unsigned)(u0 >> 32));
            y2 = __uint_as_float((unsigned)u1); y3 = __uint_as_float((unsigned)(u1 >> 32));
            y4 = __uint_as_float((unsigned)u2); y5 = __uint_as_float((unsigned)(u2 >> 32));
            y6 = __uint_as_float((unsigned)u3); y7 = __uint_as_float((unsigned)(u3 >> 32));
            if (lr == 0) {    // refresh boundary strip for next phase (reads brow[0])
                float* wp = &brow[0][rt][hi * 8];
                *reinterpret_cast<float4*>(wp)     = make_float4(y0, y1, y2, y3);
                *reinterpret_cast<float4*>(wp + 4) = make_float4(y4, y5, y6, y7);
            }
        }
        __syncthreads();
    }

    // epilogue: sigmoid + store owned rows (waves 0..3)
    if (rt < CH / 16) {
        float* op = out + ((size_t)b * TT + t0) * KK + hi * 8;
        float o0 = 1.f / (1.f + __expf(-5.f * (y0 - 0.5f)));
        float o1 = 1.f / (1.f + __expf(-5.f * (y1 - 0.5f)));
        float o2 = 1.f / (1.f + __expf(-5.f * (y2 - 0.5f)));
        float o3 = 1.f / (1.f + __expf(-5.f * (y3 - 0.5f)));
        float o4 = 1.f / (1.f + __expf(-5.f * (y4 - 0.5f)));
        float o5 = 1.f / (1.f + __expf(-5.f * (y5 - 0.5f)));
        float o6 = 1.f / (1.f + __expf(-5.f * (y6 - 0.5f)));
        float o7 = 1.f / (1.f + __expf(-5.f * (y7 - 0.5f)));
        *reinterpret_cast<float4*>(&op[0]) = make_float4(o0, o1, o2, o3);
        *reinterpret_cast<float4*>(&op[4]) = make_float4(o4, o5, o6, o7);
    }
}

extern "C" void kernel_launch(void* const* d_in, const int* in_sizes, int n_in,
                              void* d_out, int out_size, void* d_ws, size_t ws_size,
                              hipStream_t stream) {
    const float* x       = (const float*)d_in[0];
    const float* w_right = (const float*)d_in[1];
    const float* w_op    = (const float*)d_in[2];
    float* ws  = (float*)d_ws;
    float* out = (float*)d_out;

    prep_kernel<<<1, 64, 0, stream>>>(w_right, w_op, ws);
    atomx_kernel<<<BB * TT / 8, 256, 0, stream>>>(x, ws);

    void* args[] = { (void*)&ws, (void*)&out };
    hipLaunchCooperativeKernel((void*)phase_all_kernel,
                               dim3(BB * BPB), dim3(NTHR), args, 0, stream);
}